// Round 1
// baseline (2109.808 us; speedup 1.0000x reference)
//
#include <hip/hip_runtime.h>

#define HWc   262144   // 512*512
#define CGc   128
#define CHc   64
#define COc   32
#define NPIXc 524288   // B*H*W

__device__ __forceinline__ int refl(int p){
  if (p < 0) p = -p;
  else if (p >= 512) p = 1022 - p;
  return p;
}

__device__ __forceinline__ unsigned short f2bf(float x){
  unsigned u = __float_as_uint(x);
  return (unsigned short)((u + 0x7fffu + ((u >> 16) & 1u)) >> 16);
}

// ---------------- K0: spectral-norm weight (single block, 64 threads) ----------------
__global__ void k0_sn(const float* __restrict__ wbar, const float* __restrict__ u,
                      float* __restrict__ wsn){
  const int t = threadIdx.x;
  __shared__ float sv1[32];
  float tv = 0.f;
  if (t < 32){
    #pragma unroll
    for (int o = 0; o < 32; o++) tv += wbar[o*32 + t] * u[o];
  }
  float sq = tv * tv;
  #pragma unroll
  for (int off = 32; off; off >>= 1) sq += __shfl_down(sq, off);
  const float n1 = sqrtf(__shfl(sq, 0)) + 1e-12f;
  if (t < 32) sv1[t] = tv / n1;
  __syncthreads();
  float tu = 0.f;
  if (t < 32){
    #pragma unroll
    for (int c = 0; c < 32; c++) tu += wbar[t*32 + c] * sv1[c];
  }
  float sq2 = tu * tu;
  #pragma unroll
  for (int off = 32; off; off >>= 1) sq2 += __shfl_down(sq2, off);
  const float S = __shfl(sq2, 0);
  const float sigma = S / (sqrtf(S) + 1e-12f);   // u1 . (W v1)
  const float inv = 1.f / sigma;
  for (int k = t; k < 1024; k += 64) wsn[k] = wbar[k] * inv;
}

// ---------------- K1: 1x1 conv 128->64 + channel L2 normalize -> bf16 pixel-major ----
__global__ __launch_bounds__(256) void k1_gn(const float* __restrict__ f,
                                             const float* __restrict__ wg,
                                             const float* __restrict__ bg,
                                             unsigned int* __restrict__ gn){
  const int p   = blockIdx.x * 256 + threadIdx.x;
  const int b   = p >> 18;
  const int pix = p & (HWc - 1);
  const float* fb = f + (size_t)b * CGc * HWc + pix;

  float acc[CHc];
  #pragma unroll
  for (int o = 0; o < CHc; o++) acc[o] = bg[o];

  #pragma unroll 1
  for (int c = 0; c < CGc; c += 4){
    const float fv0 = fb[(size_t)(c+0) * HWc];
    const float fv1 = fb[(size_t)(c+1) * HWc];
    const float fv2 = fb[(size_t)(c+2) * HWc];
    const float fv3 = fb[(size_t)(c+3) * HWc];
    #pragma unroll
    for (int o = 0; o < CHc; o++){
      const float* wr = wg + o*CGc + c;   // uniform index -> scalar loads
      acc[o] = fmaf(wr[0], fv0, fmaf(wr[1], fv1, fmaf(wr[2], fv2, fmaf(wr[3], fv3, acc[o]))));
    }
  }
  float nsq = 0.f;
  #pragma unroll
  for (int o = 0; o < CHc; o++) nsq = fmaf(acc[o], acc[o], nsq);
  const float inv = 1.f / fmaxf(sqrtf(nsq), 1e-4f);

  uint4* gp = (uint4*)(gn + (size_t)p * 32);   // 64 bf16 = 32 uints per pixel
  #pragma unroll
  for (int k = 0; k < 8; k++){
    uint4 w;
    w.x = (unsigned)f2bf(acc[8*k+0]*inv) | ((unsigned)f2bf(acc[8*k+1]*inv) << 16);
    w.y = (unsigned)f2bf(acc[8*k+2]*inv) | ((unsigned)f2bf(acc[8*k+3]*inv) << 16);
    w.z = (unsigned)f2bf(acc[8*k+4]*inv) | ((unsigned)f2bf(acc[8*k+5]*inv) << 16);
    w.w = (unsigned)f2bf(acc[8*k+6]*inv) | ((unsigned)f2bf(acc[8*k+7]*inv) << 16);
    gp[k] = w;
  }
}

// ---------------- K2: 48-tap correlation + softmax + alpha agg + SN matvec -> y2 ------
__global__ __launch_bounds__(256) void k2_agg(const unsigned int* __restrict__ gn,
                                              const float* __restrict__ alpha,
                                              const float* __restrict__ wsn,
                                              float* __restrict__ y2){
  const int p   = blockIdx.x * 256 + threadIdx.x;
  const int b   = p >> 18;
  const int pix = p & (HWc - 1);
  const int yy  = pix >> 9;
  const int xx  = pix & 511;

  float cv[CHc];
  {
    const uint4* cp = (const uint4*)(gn + (size_t)p * 32);
    #pragma unroll
    for (int k = 0; k < 8; k++){
      const uint4 tq = cp[k];
      const unsigned vv[4] = {tq.x, tq.y, tq.z, tq.w};
      #pragma unroll
      for (int m = 0; m < 4; m++){
        cv[8*k + 2*m]     = __uint_as_float(vv[m] << 16);
        cv[8*k + 2*m + 1] = __uint_as_float(vv[m] & 0xffff0000u);
      }
    }
  }

  float yacc[COc];
  #pragma unroll
  for (int o = 0; o < COc; o++) yacc[o] = 0.f;
  float esum = 0.f;
  const float* ab = alpha + (size_t)b * COc * HWc;

  #pragma unroll 1
  for (int i = 0; i < 7; i++){
    const int ny = refl(yy + i - 3);
    #pragma unroll 1
    for (int j = 0; j < 7; j++){
      if (i == 3 && j == 3) continue;
      const int nx = refl(xx + j - 3);
      const int npix = (ny << 9) + nx;
      float s = 0.f;
      {
        const uint4* qp = (const uint4*)(gn + ((size_t)(b << 18) + npix) * 32);
        #pragma unroll
        for (int k = 0; k < 8; k++){
          const uint4 tq = qp[k];
          const unsigned vv[4] = {tq.x, tq.y, tq.z, tq.w};
          #pragma unroll
          for (int m = 0; m < 4; m++){
            s = fmaf(cv[8*k + 2*m],     __uint_as_float(vv[m] << 16), s);
            s = fmaf(cv[8*k + 2*m + 1], __uint_as_float(vv[m] & 0xffff0000u), s);
          }
        }
      }
      // scores are dots of unit vectors (|s|<=~1): exp(s) directly == softmax w/ max folded out
      const float e = __expf(s);
      esum += e;
      #pragma unroll
      for (int o = 0; o < COc; o++)
        yacc[o] = fmaf(e, ab[(size_t)o * HWc + npix], yacc[o]);
    }
  }

  const float inv = 1.f / esum;
  float* yp = y2 + (size_t)p * 32;
  #pragma unroll 1
  for (int o = 0; o < COc; o += 4){
    float s0 = 0.f, s1 = 0.f, s2 = 0.f, s3 = 0.f;
    #pragma unroll
    for (int c = 0; c < COc; c++){
      const float yv = yacc[c];
      s0 = fmaf(wsn[(o+0)*32 + c], yv, s0);
      s1 = fmaf(wsn[(o+1)*32 + c], yv, s1);
      s2 = fmaf(wsn[(o+2)*32 + c], yv, s2);
      s3 = fmaf(wsn[(o+3)*32 + c], yv, s3);
    }
    yp[o+0] = s0 * inv; yp[o+1] = s1 * inv; yp[o+2] = s2 * inv; yp[o+3] = s3 * inv;
  }
}

// ---------------- K3: BN stats (per-channel sum, sumsq) -------------------------------
__global__ __launch_bounds__(256) void k3_stats(const float* __restrict__ y2,
                                                float* __restrict__ stats){
  float s[COc], q[COc];
  #pragma unroll
  for (int o = 0; o < COc; o++){ s[o] = 0.f; q[o] = 0.f; }
  const int stride = gridDim.x * 256;
  for (int p = blockIdx.x * 256 + threadIdx.x; p < NPIXc; p += stride){
    const float4* yp = (const float4*)(y2 + (size_t)p * 32);
    #pragma unroll
    for (int k = 0; k < 8; k++){
      const float4 t4 = yp[k];
      s[4*k+0] += t4.x; q[4*k+0] = fmaf(t4.x, t4.x, q[4*k+0]);
      s[4*k+1] += t4.y; q[4*k+1] = fmaf(t4.y, t4.y, q[4*k+1]);
      s[4*k+2] += t4.z; q[4*k+2] = fmaf(t4.z, t4.z, q[4*k+2]);
      s[4*k+3] += t4.w; q[4*k+3] = fmaf(t4.w, t4.w, q[4*k+3]);
    }
  }
  #pragma unroll
  for (int o = 0; o < COc; o++){
    #pragma unroll
    for (int off = 32; off; off >>= 1){
      s[o] += __shfl_down(s[o], off);
      q[o] += __shfl_down(q[o], off);
    }
  }
  if ((threadIdx.x & 63) == 0){
    #pragma unroll
    for (int o = 0; o < COc; o++){
      atomicAdd(&stats[o], s[o]);
      atomicAdd(&stats[COc + o], q[o]);
    }
  }
}

// ---------------- K4: BatchNorm + residual -------------------------------------------
__global__ __launch_bounds__(256) void k4_out(const float* __restrict__ y2,
                                              const float* __restrict__ alpha,
                                              const float* __restrict__ stats,
                                              float* __restrict__ out){
  const int p   = blockIdx.x * 256 + threadIdx.x;
  const int b   = p >> 18;
  const int pix = p & (HWc - 1);
  const float* yp = y2 + (size_t)p * 32;
  const size_t boff = (size_t)b * COc * HWc + pix;
  const float invN = 1.f / (float)NPIXc;
  #pragma unroll 1
  for (int o = 0; o < COc; o++){
    const float mean = stats[o] * invN;
    const float var  = fmaf(-mean, mean, stats[COc + o] * invN);
    const float sc   = 0.1f * rsqrtf(var + 1e-5f);
    out[boff + (size_t)o * HWc] = fmaf(yp[o] - mean, sc, alpha[boff + (size_t)o * HWc]);
  }
}

extern "C" void kernel_launch(void* const* d_in, const int* in_sizes, int n_in,
                              void* d_out, int out_size, void* d_ws, size_t ws_size,
                              hipStream_t stream){
  const float* f     = (const float*)d_in[0];
  const float* alpha = (const float*)d_in[1];
  const float* wg    = (const float*)d_in[2];
  const float* bg    = (const float*)d_in[3];
  const float* wbar  = (const float*)d_in[4];
  const float* u     = (const float*)d_in[5];
  (void)in_sizes; (void)n_in; (void)out_size; (void)ws_size;
  float* out = (float*)d_out;

  char* ws = (char*)d_ws;
  float* wsn   = (float*)ws;             // 1024 f32
  float* stats = (float*)(ws + 4096);    // 64 f32
  unsigned int* gn = (unsigned int*)(ws + 8192);                       // 64 MB (bf16 x 64ch, pixel-major)
  float* y2 = (float*)(ws + 8192 + (size_t)NPIXc * 32 * sizeof(unsigned)); // 64 MB f32 pixel-major

  hipMemsetAsync(stats, 0, 64 * sizeof(float), stream);
  k0_sn<<<1, 64, 0, stream>>>(wbar, u, wsn);
  k1_gn<<<NPIXc / 256, 256, 0, stream>>>(f, wg, bg, gn);
  k2_agg<<<NPIXc / 256, 256, 0, stream>>>(gn, alpha, wsn, y2);
  k3_stats<<<512, 256, 0, stream>>>(y2, stats);
  k4_out<<<NPIXc / 256, 256, 0, stream>>>(y2, alpha, stats, out);
}

// Round 2
// 703.336 us; speedup vs baseline: 2.9997x; 2.9997x over previous
//
#include <hip/hip_runtime.h>

#define HWc   262144   // 512*512
#define CGc   128
#define CHc   64
#define COc   32
#define NPIXc 524288   // B*H*W
#define TW 32
#define TH 8
#define HLW 38         // TW+6
#define HLH 14         // TH+6
#define HPX (HLW*HLH)  // 532

__device__ __forceinline__ int refl(int p){
  if (p < 0) p = -p;
  else if (p >= 512) p = 1022 - p;
  return p;
}
__device__ __forceinline__ unsigned short f2bf(float x){
  unsigned u = __float_as_uint(x);
  return (unsigned short)((u + 0x7fffu + ((u >> 16) & 1u)) >> 16);
}
__device__ __forceinline__ unsigned pack2(float a, float b){
  return (unsigned)f2bf(a) | ((unsigned)f2bf(b) << 16);
}
__device__ __forceinline__ float blo(unsigned w){ return __uint_as_float(w << 16); }
__device__ __forceinline__ float bhi(unsigned w){ return __uint_as_float(w & 0xffff0000u); }

// ---------------- K0: spectral-norm weight (single block, 64 threads) ----------------
__global__ void k0_sn(const float* __restrict__ wbar, const float* __restrict__ u,
                      float* __restrict__ wsn){
  const int t = threadIdx.x;
  __shared__ float sv1[32];
  float tv = 0.f;
  if (t < 32){
    #pragma unroll
    for (int o = 0; o < 32; o++) tv += wbar[o*32 + t] * u[o];
  }
  float sq = tv * tv;
  #pragma unroll
  for (int off = 32; off; off >>= 1) sq += __shfl_down(sq, off);
  const float n1 = sqrtf(__shfl(sq, 0)) + 1e-12f;
  if (t < 32) sv1[t] = tv / n1;
  __syncthreads();
  float tu = 0.f;
  if (t < 32){
    #pragma unroll
    for (int c = 0; c < 32; c++) tu += wbar[t*32 + c] * sv1[c];
  }
  float sq2 = tu * tu;
  #pragma unroll
  for (int off = 32; off; off >>= 1) sq2 += __shfl_down(sq2, off);
  const float S = __shfl(sq2, 0);
  const float sigma = S / (sqrtf(S) + 1e-12f);   // u1 . (W v1)
  const float inv = 1.f / sigma;
  for (int k = t; k < 1024; k += 64) wsn[k] = wbar[k] * inv;
}

// ---------------- K1: 1x1 conv 128->64 + channel L2 normalize -> bf16 pixel-major ----
__global__ __launch_bounds__(256) void k1_gn(const float* __restrict__ f,
                                             const float* __restrict__ wg,
                                             const float* __restrict__ bg,
                                             unsigned int* __restrict__ gn){
  const int p   = blockIdx.x * 256 + threadIdx.x;
  const int b   = p >> 18;
  const int pix = p & (HWc - 1);
  const float* fb = f + (size_t)b * CGc * HWc + pix;

  float acc[CHc];
  #pragma unroll
  for (int o = 0; o < CHc; o++) acc[o] = bg[o];

  #pragma unroll 1
  for (int c = 0; c < CGc; c += 4){
    const float fv0 = fb[(size_t)(c+0) * HWc];
    const float fv1 = fb[(size_t)(c+1) * HWc];
    const float fv2 = fb[(size_t)(c+2) * HWc];
    const float fv3 = fb[(size_t)(c+3) * HWc];
    #pragma unroll
    for (int o = 0; o < CHc; o++){
      const float* wr = wg + o*CGc + c;   // uniform index -> scalar loads
      acc[o] = fmaf(wr[0], fv0, fmaf(wr[1], fv1, fmaf(wr[2], fv2, fmaf(wr[3], fv3, acc[o]))));
    }
  }
  float nsq = 0.f;
  #pragma unroll
  for (int o = 0; o < CHc; o++) nsq = fmaf(acc[o], acc[o], nsq);
  const float inv = 1.f / fmaxf(sqrtf(nsq), 1e-4f);

  uint4* gp = (uint4*)(gn + (size_t)p * 32);   // 64 bf16 = 32 uints per pixel
  #pragma unroll
  for (int k = 0; k < 8; k++){
    uint4 w;
    w.x = pack2(acc[8*k+0]*inv, acc[8*k+1]*inv);
    w.y = pack2(acc[8*k+2]*inv, acc[8*k+3]*inv);
    w.z = pack2(acc[8*k+4]*inv, acc[8*k+5]*inv);
    w.w = pack2(acc[8*k+6]*inv, acc[8*k+7]*inv);
    gp[k] = w;
  }
}

// ---------------- K2a: alpha -> pixel-major bf16 (32 ch = 16 u32 per px) -------------
__global__ __launch_bounds__(256) void k2a_alpha(const float* __restrict__ alpha,
                                                 unsigned int* __restrict__ apm){
  const int p   = blockIdx.x * 256 + threadIdx.x;
  const int b   = p >> 18;
  const int pix = p & (HWc - 1);
  const float* ab = alpha + (size_t)b * COc * HWc + pix;
  uint4* op = (uint4*)(apm + (size_t)p * 16);
  #pragma unroll
  for (int k = 0; k < 4; k++){
    uint4 w;
    w.x = pack2(ab[(size_t)(8*k+0)*HWc], ab[(size_t)(8*k+1)*HWc]);
    w.y = pack2(ab[(size_t)(8*k+2)*HWc], ab[(size_t)(8*k+3)*HWc]);
    w.z = pack2(ab[(size_t)(8*k+4)*HWc], ab[(size_t)(8*k+5)*HWc]);
    w.w = pack2(ab[(size_t)(8*k+6)*HWc], ab[(size_t)(8*k+7)*HWc]);
    op[k] = w;
  }
}

// ---------------- K2: tiled correlation + softmax + agg + SN matvec -> y2 (bf16) -----
__global__ __launch_bounds__(256) void k2_agg(const unsigned int* __restrict__ gn,
                                              const unsigned int* __restrict__ apm,
                                              const float* __restrict__ wsn,
                                              unsigned int* __restrict__ y2){
  __shared__ unsigned int gs[HPX * 32];   // 68096 B, uint4-swizzled

  // XCD-chunked block swizzle (2048 blocks, 256 per XCD chunk)
  const int lb  = (blockIdx.x & 7) * 256 + (blockIdx.x >> 3);
  const int txx = lb & 15;
  const int tyy = (lb >> 4) & 63;
  const int bb  = lb >> 10;
  const int x0  = txx * TW, y0 = tyy * TH;
  const int tid = threadIdx.x;

  // ---- stage gn halo tile into LDS (XOR-swizzled uint4 slots) ----
  for (int t = tid; t < HPX; t += 256){
    const int hr = t / HLW;
    const int hc = t - hr * HLW;
    const int gy = refl(y0 + hr - 3);
    const int gx = refl(x0 + hc - 3);
    const uint4* src = (const uint4*)(gn + (size_t)((bb << 18) + (gy << 9) + gx) * 32);
    uint4* dst = (uint4*)(gs + t * 32);
    #pragma unroll
    for (int k = 0; k < 8; k++) dst[k ^ (t & 7)] = src[k];
  }
  __syncthreads();

  const int r  = tid >> 5, c = tid & 31;
  const int yy = y0 + r,  xx = x0 + c;
  const int self = (r + 3) * HLW + (c + 3);

  float cv[CHc];
  {
    const uint4* sp = (const uint4*)(gs + self * 32);
    #pragma unroll
    for (int k = 0; k < 8; k++){
      const uint4 q = sp[k ^ (self & 7)];
      const unsigned vv[4] = {q.x, q.y, q.z, q.w};
      #pragma unroll
      for (int m = 0; m < 4; m++){
        cv[8*k + 2*m]     = blo(vv[m]);
        cv[8*k + 2*m + 1] = bhi(vv[m]);
      }
    }
  }

  float yacc[COc];
  #pragma unroll
  for (int o = 0; o < COc; o++) yacc[o] = 0.f;
  float esum = 0.f;

  #pragma unroll 1
  for (int i = 0; i < 7; i++){
    const int ay = refl(yy + i - 3);
    const int rowbase = (r + i) * HLW + c;
    #pragma unroll
    for (int j = 0; j < 7; j++){
      const int hp = rowbase + j;
      float s = 0.f;
      {
        const uint4* np = (const uint4*)(gs + hp * 32);
        #pragma unroll
        for (int k = 0; k < 8; k++){
          const uint4 q = np[k ^ (hp & 7)];
          const unsigned vv[4] = {q.x, q.y, q.z, q.w};
          #pragma unroll
          for (int m = 0; m < 4; m++){
            s = fmaf(cv[8*k + 2*m],     blo(vv[m]), s);
            s = fmaf(cv[8*k + 2*m + 1], bhi(vv[m]), s);
          }
        }
      }
      // center tap: e = 0 exactly (ref: exp(-10000) underflows to 0)
      const float e = (j == 3 && i == 3) ? 0.f : __expf(s);
      esum += e;
      const int ax = refl(xx + j - 3);
      const uint4* ap = (const uint4*)(apm + (size_t)((bb << 18) + (ay << 9) + ax) * 16);
      #pragma unroll
      for (int k = 0; k < 4; k++){
        const uint4 q = ap[k];
        const unsigned vv[4] = {q.x, q.y, q.z, q.w};
        #pragma unroll
        for (int m = 0; m < 4; m++){
          yacc[8*k + 2*m]     = fmaf(e, blo(vv[m]), yacc[8*k + 2*m]);
          yacc[8*k + 2*m + 1] = fmaf(e, bhi(vv[m]), yacc[8*k + 2*m + 1]);
        }
      }
    }
  }

  const float inv = 1.f / esum;
  unsigned yw[16];
  #pragma unroll
  for (int o = 0; o < COc; o += 2){
    float s0 = 0.f, s1 = 0.f;
    #pragma unroll
    for (int cc = 0; cc < COc; cc++){
      s0 = fmaf(wsn[(o+0)*32 + cc], yacc[cc], s0);
      s1 = fmaf(wsn[(o+1)*32 + cc], yacc[cc], s1);
    }
    yw[o >> 1] = pack2(s0 * inv, s1 * inv);
  }
  uint4* yp = (uint4*)(y2 + (size_t)((bb << 18) + (yy << 9) + xx) * 16);
  #pragma unroll
  for (int k = 0; k < 4; k++)
    yp[k] = make_uint4(yw[4*k], yw[4*k+1], yw[4*k+2], yw[4*k+3]);
}

// ---------------- K3: BN stats (per-channel sum, sumsq) over bf16 y2 ------------------
__global__ __launch_bounds__(256) void k3_stats(const unsigned int* __restrict__ y2,
                                                float* __restrict__ stats){
  float s[COc], q[COc];
  #pragma unroll
  for (int o = 0; o < COc; o++){ s[o] = 0.f; q[o] = 0.f; }
  const int stride = gridDim.x * 256;
  for (int p = blockIdx.x * 256 + threadIdx.x; p < NPIXc; p += stride){
    const uint4* yp = (const uint4*)(y2 + (size_t)p * 16);
    #pragma unroll
    for (int k = 0; k < 4; k++){
      const uint4 w = yp[k];
      const unsigned vv[4] = {w.x, w.y, w.z, w.w};
      #pragma unroll
      for (int m = 0; m < 4; m++){
        const float a = blo(vv[m]), b = bhi(vv[m]);
        s[8*k+2*m]   += a; q[8*k+2*m]   = fmaf(a, a, q[8*k+2*m]);
        s[8*k+2*m+1] += b; q[8*k+2*m+1] = fmaf(b, b, q[8*k+2*m+1]);
      }
    }
  }
  #pragma unroll
  for (int o = 0; o < COc; o++){
    #pragma unroll
    for (int off = 32; off; off >>= 1){
      s[o] += __shfl_down(s[o], off);
      q[o] += __shfl_down(q[o], off);
    }
  }
  __shared__ float red[4][64];
  const int wv = threadIdx.x >> 6;
  if ((threadIdx.x & 63) == 0){
    #pragma unroll
    for (int o = 0; o < COc; o++){ red[wv][o] = s[o]; red[wv][32 + o] = q[o]; }
  }
  __syncthreads();
  if (threadIdx.x < 64){
    const float v = red[0][threadIdx.x] + red[1][threadIdx.x]
                  + red[2][threadIdx.x] + red[3][threadIdx.x];
    atomicAdd(&stats[threadIdx.x], v);
  }
}

// ---------------- K3b: stats -> (mean, 0.1*rsqrt(var+eps)) ---------------------------
__global__ void k3b_final(const float* __restrict__ stats, float* __restrict__ stats2){
  const int t = threadIdx.x;
  if (t < COc){
    const float invN = 1.f / (float)NPIXc;
    const float mean = stats[t] * invN;
    const float var  = fmaf(-mean, mean, stats[COc + t] * invN);
    stats2[t]       = mean;
    stats2[COc + t] = 0.1f * rsqrtf(var + 1e-5f);
  }
}

// ---------------- K4: BatchNorm + residual -------------------------------------------
__global__ __launch_bounds__(256) void k4_out(const unsigned int* __restrict__ y2,
                                              const float* __restrict__ alpha,
                                              const float* __restrict__ stats2,
                                              float* __restrict__ out){
  const int p   = blockIdx.x * 256 + threadIdx.x;
  const int b   = p >> 18;
  const int pix = p & (HWc - 1);
  const uint4* yp = (const uint4*)(y2 + (size_t)p * 16);
  const size_t boff = (size_t)b * COc * HWc + pix;
  #pragma unroll
  for (int k = 0; k < 4; k++){
    const uint4 w = yp[k];
    const unsigned vv[4] = {w.x, w.y, w.z, w.w};
    #pragma unroll
    for (int m = 0; m < 4; m++){
      const int o = 8*k + 2*m;
      out[boff + (size_t)o*HWc]     = fmaf(blo(vv[m]) - stats2[o],   stats2[COc+o],
                                           alpha[boff + (size_t)o*HWc]);
      out[boff + (size_t)(o+1)*HWc] = fmaf(bhi(vv[m]) - stats2[o+1], stats2[COc+o+1],
                                           alpha[boff + (size_t)(o+1)*HWc]);
    }
  }
}

extern "C" void kernel_launch(void* const* d_in, const int* in_sizes, int n_in,
                              void* d_out, int out_size, void* d_ws, size_t ws_size,
                              hipStream_t stream){
  const float* f     = (const float*)d_in[0];
  const float* alpha = (const float*)d_in[1];
  const float* wg    = (const float*)d_in[2];
  const float* bg    = (const float*)d_in[3];
  const float* wbar  = (const float*)d_in[4];
  const float* u     = (const float*)d_in[5];
  (void)in_sizes; (void)n_in; (void)out_size; (void)ws_size;
  float* out = (float*)d_out;

  char* ws = (char*)d_ws;
  float* wsn    = (float*)ws;                                  // 4 KB
  float* stats  = (float*)(ws + 4096);                         // 4 KB
  float* stats2 = (float*)(ws + 8192);                         // 8 KB pad
  unsigned int* apm = (unsigned int*)(ws + 16384);             // 32 MB alpha bf16 px-major
  unsigned int* gn  = (unsigned int*)(ws + 16384 + (size_t)NPIXc*64);            // 64 MB
  unsigned int* y2  = (unsigned int*)(ws + 16384 + (size_t)NPIXc*64 + (size_t)NPIXc*128); // 32 MB

  hipMemsetAsync(stats, 0, 64 * sizeof(float), stream);
  k0_sn    <<<1, 64, 0, stream>>>(wbar, u, wsn);
  k2a_alpha<<<NPIXc / 256, 256, 0, stream>>>(alpha, apm);
  k1_gn    <<<NPIXc / 256, 256, 0, stream>>>(f, wg, bg, gn);
  k2_agg   <<<2048, 256, 0, stream>>>(gn, apm, wsn, y2);
  k3_stats <<<256, 256, 0, stream>>>(y2, stats);
  k3b_final<<<1, 64, 0, stream>>>(stats, stats2);
  k4_out   <<<NPIXc / 256, 256, 0, stream>>>(y2, alpha, stats2, out);
}

// Round 4
// 330.041 us; speedup vs baseline: 6.3926x; 2.1311x over previous
//
#include <hip/hip_runtime.h>

#define HWc   262144   // 512*512
#define CGc   128
#define CHc   64
#define COc   32
#define NPIXc 524288   // B*H*W
#define TW 32
#define TH 8
#define HLW 38         // TW+6
#define HLH 14         // TH+6
#define HPX (HLW*HLH)  // 532

typedef _Float16 h2 __attribute__((ext_vector_type(2)));

__device__ __forceinline__ int refl(int p){
  if (p < 0) p = -p;
  else if (p >= 512) p = 1022 - p;
  return p;
}
__device__ __forceinline__ h2 as_h2(unsigned u){ union{unsigned u; h2 h;} x; x.u = u; return x.h; }
__device__ __forceinline__ unsigned as_u(h2 h){ union{unsigned u; h2 h;} x; x.h = h; return x.u; }
// pack two f32 -> 2xf16 (RNE via standard casts)
__device__ __forceinline__ unsigned pkh(float a, float b){
  h2 h; h.x = (_Float16)a; h.y = (_Float16)b; return as_u(h);
}
__device__ __forceinline__ float2 upk(unsigned u){
  h2 h = as_h2(u); return make_float2((float)h.x, (float)h.y);
}
// d = a.f16[0]*b.f16[0] + a.f16[1]*b.f16[1] + c   (v_dot2_f32_f16)
__device__ __forceinline__ float dot2h(unsigned a, unsigned b, float c){
  return __builtin_amdgcn_fdot2(as_h2(a), as_h2(b), c, false);
}
// packed fp32 fma: d = a*b + c (2 lanes) — numerically validated in R3
__device__ __forceinline__ float2 pkfma(float2 a, float2 b, float2 c){
  float2 d;
  asm("v_pk_fma_f32 %0, %1, %2, %3" : "=v"(d) : "v"(a), "v"(b), "v"(c));
  return d;
}

// -------- K0: sigma, pack w_sn and wg to f16 pairs -----------------------------------
__global__ void k0_prep(const float* __restrict__ wbar, const float* __restrict__ u,
                        const float* __restrict__ wg,
                        unsigned* __restrict__ wsnb, unsigned* __restrict__ wgb){
  const int t = threadIdx.x;
  __shared__ float sv1[32];
  float tv = 0.f;
  if (t < 32){
    #pragma unroll
    for (int o = 0; o < 32; o++) tv += wbar[o*32 + t] * u[o];
  }
  float sq = tv * tv;
  #pragma unroll
  for (int off = 32; off; off >>= 1) sq += __shfl_down(sq, off);
  const float n1 = sqrtf(__shfl(sq, 0)) + 1e-12f;
  if (t < 32) sv1[t] = tv / n1;
  __syncthreads();
  float tu = 0.f;
  if (t < 32){
    #pragma unroll
    for (int c = 0; c < 32; c++) tu += wbar[t*32 + c] * sv1[c];
  }
  float sq2 = tu * tu;
  #pragma unroll
  for (int off = 32; off; off >>= 1) sq2 += __shfl_down(sq2, off);
  const float S = __shfl(sq2, 0);
  const float inv = (sqrtf(S) + 1e-12f) / S;     // 1/sigma
  for (int k = t; k < 512; k += 64){             // wsnb[o][p], 16 pairs per row
    const int o = k >> 4, p = k & 15;
    wsnb[k] = pkh(wbar[o*32 + 2*p] * inv, wbar[o*32 + 2*p + 1] * inv);
  }
  for (int k = t; k < 4096; k += 64){            // wgb[o][p], 64 pairs per row
    const int o = k >> 6, p = k & 63;
    wgb[k] = pkh(wg[o*128 + 2*p], wg[o*128 + 2*p + 1]);
  }
}

// -------- K1: 1x1 conv 128->64 (f16 dot2) + L2 normalize -> gn f16 px-major ----------
__global__ __launch_bounds__(256) void k1_gn(const float* __restrict__ f,
                                             const unsigned* __restrict__ wgb,
                                             const float* __restrict__ bg,
                                             unsigned* __restrict__ gn){
  const int p   = blockIdx.x * 256 + threadIdx.x;
  const int b   = p >> 18;
  const int pix = p & (HWc - 1);
  const float* fb = f + (size_t)b * CGc * HWc + pix;

  float acc[CHc];
  #pragma unroll
  for (int o = 0; o < CHc; o++) acc[o] = bg[o];

  #pragma unroll 1
  for (int pp = 0; pp < 64; pp += 4){   // 4 channel-pairs = 8 channels per iter
    unsigned fp[4];
    #pragma unroll
    for (int m = 0; m < 4; m++)
      fp[m] = pkh(fb[(size_t)(2*(pp+m)) * HWc], fb[(size_t)(2*(pp+m)+1) * HWc]);
    #pragma unroll
    for (int o = 0; o < CHc; o++){
      float a = acc[o];
      a = dot2h(fp[0], wgb[o*64 + pp + 0], a);
      a = dot2h(fp[1], wgb[o*64 + pp + 1], a);
      a = dot2h(fp[2], wgb[o*64 + pp + 2], a);
      a = dot2h(fp[3], wgb[o*64 + pp + 3], a);
      acc[o] = a;
    }
  }
  float nsq = 0.f;
  #pragma unroll
  for (int o = 0; o < CHc; o++) nsq = fmaf(acc[o], acc[o], nsq);
  const float inv = 1.f / fmaxf(sqrtf(nsq), 1e-4f);

  uint4* gp = (uint4*)(gn + (size_t)p * 32);
  #pragma unroll
  for (int k = 0; k < 8; k++){
    uint4 w;
    w.x = pkh(acc[8*k+0]*inv, acc[8*k+1]*inv);
    w.y = pkh(acc[8*k+2]*inv, acc[8*k+3]*inv);
    w.z = pkh(acc[8*k+4]*inv, acc[8*k+5]*inv);
    w.w = pkh(acc[8*k+6]*inv, acc[8*k+7]*inv);
    gp[k] = w;
  }
}

// -------- K2a: alpha' = W_sn * alpha  -> f16 pixel-major (16 u32/px) -----------------
__global__ __launch_bounds__(256) void k2a_at(const float* __restrict__ alpha,
                                              const unsigned* __restrict__ wsnb,
                                              unsigned* __restrict__ apm){
  const int p   = blockIdx.x * 256 + threadIdx.x;
  const int b   = p >> 18;
  const int pix = p & (HWc - 1);
  const float* ab = alpha + (size_t)b * COc * HWc + pix;
  unsigned a16[16];
  #pragma unroll
  for (int k = 0; k < 16; k++)
    a16[k] = pkh(ab[(size_t)(2*k) * HWc], ab[(size_t)(2*k+1) * HWc]);
  unsigned ow[16];
  #pragma unroll
  for (int o = 0; o < COc; o += 2){
    float s0 = 0.f, s1 = 0.f;
    #pragma unroll
    for (int k = 0; k < 16; k++){
      s0 = dot2h(a16[k], wsnb[(o+0)*16 + k], s0);
      s1 = dot2h(a16[k], wsnb[(o+1)*16 + k], s1);
    }
    ow[o >> 1] = pkh(s0, s1);
  }
  uint4* op = (uint4*)(apm + (size_t)p * 16);
  #pragma unroll
  for (int k = 0; k < 4; k++)
    op[k] = make_uint4(ow[4*k], ow[4*k+1], ow[4*k+2], ow[4*k+3]);
}

// -------- K2: correlation (f16 dot2) + softmax + alpha' aggregation -> y2 f16 --------
__global__ __launch_bounds__(256) void k2_agg(const unsigned* __restrict__ gn,
                                              const unsigned* __restrict__ apm,
                                              unsigned* __restrict__ y2){
  __shared__ uint4 gs4[8][HPX];   // 8 channel-pair planes, lane-contiguous 16B

  const int lb  = (blockIdx.x & 7) * 256 + (blockIdx.x >> 3);   // XCD-chunked swizzle
  const int txx = lb & 15;
  const int tyy = (lb >> 4) & 63;
  const int bb  = lb >> 10;
  const int x0  = txx * TW, y0 = tyy * TH;
  const int tid = threadIdx.x;

  for (int t = tid; t < HPX; t += 256){
    const int hr = t / HLW;
    const int hc = t - hr * HLW;
    const int gy = refl(y0 + hr - 3);
    const int gx = refl(x0 + hc - 3);
    const uint4* src = (const uint4*)(gn + (size_t)((bb << 18) + (gy << 9) + gx) * 32);
    #pragma unroll
    for (int k = 0; k < 8; k++) gs4[k][t] = src[k];
  }
  __syncthreads();

  const int r  = tid >> 5, c = tid & 31;
  const int yy = y0 + r,  xx = x0 + c;
  const int self = (r + 3) * HLW + (c + 3);

  uint4 cv[8];
  #pragma unroll
  for (int k = 0; k < 8; k++) cv[k] = gs4[k][self];

  int ax[7];
  #pragma unroll
  for (int j = 0; j < 7; j++) ax[j] = refl(xx + j - 3);

  float2 yac[16];
  #pragma unroll
  for (int k = 0; k < 16; k++) yac[k] = make_float2(0.f, 0.f);
  float esum = 0.f;

  #pragma unroll 1
  for (int i = 0; i < 7; i++){
    const int ay = refl(yy + i - 3);
    const unsigned* aprow = apm + (size_t)((bb << 18) + (ay << 9)) * 16;
    const int rowbase = (r + i) * HLW + c;
    #pragma unroll
    for (int j = 0; j < 7; j++){
      if (i == 3 && j == 3) continue;          // center tap: exp(-10000) == 0
      const int hp = rowbase + j;
      float s0 = 0.f, s1 = 0.f, s2 = 0.f, s3 = 0.f;
      #pragma unroll
      for (int k = 0; k < 8; k++){
        const uint4 q = gs4[k][hp];
        s0 = dot2h(cv[k].x, q.x, s0);
        s1 = dot2h(cv[k].y, q.y, s1);
        s2 = dot2h(cv[k].z, q.z, s2);
        s3 = dot2h(cv[k].w, q.w, s3);
      }
      // |s|<=1 (unit vectors): exp(s) directly == softmax with max folded out
      const float e = __expf((s0 + s1) + (s2 + s3));
      esum += e;
      const float2 e2 = make_float2(e, e);
      const uint4* ap = (const uint4*)(aprow + (size_t)ax[j] * 16);
      #pragma unroll
      for (int kk = 0; kk < 4; kk++){
        const uint4 a = ap[kk];
        yac[4*kk+0] = pkfma(upk(a.x), e2, yac[4*kk+0]);
        yac[4*kk+1] = pkfma(upk(a.y), e2, yac[4*kk+1]);
        yac[4*kk+2] = pkfma(upk(a.z), e2, yac[4*kk+2]);
        yac[4*kk+3] = pkfma(upk(a.w), e2, yac[4*kk+3]);
      }
    }
  }

  const float inv = 1.f / esum;
  unsigned yw[16];
  #pragma unroll
  for (int k = 0; k < 16; k++) yw[k] = pkh(yac[k].x * inv, yac[k].y * inv);
  uint4* yp = (uint4*)(y2 + (size_t)((bb << 18) + (yy << 9) + xx) * 16);
  #pragma unroll
  for (int k = 0; k < 4; k++)
    yp[k] = make_uint4(yw[4*k], yw[4*k+1], yw[4*k+2], yw[4*k+3]);
}

// -------- K3: BN stats over f16 y2 ---------------------------------------------------
__global__ __launch_bounds__(256) void k3_stats(const unsigned* __restrict__ y2,
                                                float* __restrict__ stats){
  float s[COc], q[COc];
  #pragma unroll
  for (int o = 0; o < COc; o++){ s[o] = 0.f; q[o] = 0.f; }
  const int stride = gridDim.x * 256;
  for (int p = blockIdx.x * 256 + threadIdx.x; p < NPIXc; p += stride){
    const uint4* yp = (const uint4*)(y2 + (size_t)p * 16);
    #pragma unroll
    for (int k = 0; k < 4; k++){
      const uint4 w = yp[k];
      const unsigned vv[4] = {w.x, w.y, w.z, w.w};
      #pragma unroll
      for (int m = 0; m < 4; m++){
        const float2 ab = upk(vv[m]);
        s[8*k+2*m]   += ab.x; q[8*k+2*m]   = fmaf(ab.x, ab.x, q[8*k+2*m]);
        s[8*k+2*m+1] += ab.y; q[8*k+2*m+1] = fmaf(ab.y, ab.y, q[8*k+2*m+1]);
      }
    }
  }
  #pragma unroll
  for (int o = 0; o < COc; o++){
    #pragma unroll
    for (int off = 32; off; off >>= 1){
      s[o] += __shfl_down(s[o], off);
      q[o] += __shfl_down(q[o], off);
    }
  }
  __shared__ float red[4][64];
  const int wv = threadIdx.x >> 6;
  if ((threadIdx.x & 63) == 0){
    #pragma unroll
    for (int o = 0; o < COc; o++){ red[wv][o] = s[o]; red[wv][32 + o] = q[o]; }
  }
  __syncthreads();
  if (threadIdx.x < 64){
    const float v = red[0][threadIdx.x] + red[1][threadIdx.x]
                  + red[2][threadIdx.x] + red[3][threadIdx.x];
    atomicAdd(&stats[threadIdx.x], v);
  }
}

// -------- K3b: stats -> (mean, 0.1*rsqrt(var+eps)) ------------------------------------
__global__ void k3b_final(const float* __restrict__ stats, float* __restrict__ stats2){
  const int t = threadIdx.x;
  if (t < COc){
    const float invN = 1.f / (float)NPIXc;
    const float mean = stats[t] * invN;
    const float var  = fmaf(-mean, mean, stats[COc + t] * invN);
    stats2[t]       = mean;
    stats2[COc + t] = 0.1f * rsqrtf(var + 1e-5f);
  }
}

// -------- K4: BatchNorm + residual ----------------------------------------------------
__global__ __launch_bounds__(256) void k4_out(const unsigned* __restrict__ y2,
                                              const float* __restrict__ alpha,
                                              const float* __restrict__ stats2,
                                              float* __restrict__ out){
  const int p   = blockIdx.x * 256 + threadIdx.x;
  const int b   = p >> 18;
  const int pix = p & (HWc - 1);
  const uint4* yp = (const uint4*)(y2 + (size_t)p * 16);
  const size_t boff = (size_t)b * COc * HWc + pix;
  #pragma unroll
  for (int k = 0; k < 4; k++){
    const uint4 w = yp[k];
    const unsigned vv[4] = {w.x, w.y, w.z, w.w};
    #pragma unroll
    for (int m = 0; m < 4; m++){
      const int o = 8*k + 2*m;
      const float2 ab = upk(vv[m]);
      out[boff + (size_t)o*HWc]     = fmaf(ab.x - stats2[o],   stats2[COc+o],
                                           alpha[boff + (size_t)o*HWc]);
      out[boff + (size_t)(o+1)*HWc] = fmaf(ab.y - stats2[o+1], stats2[COc+o+1],
                                           alpha[boff + (size_t)(o+1)*HWc]);
    }
  }
}

extern "C" void kernel_launch(void* const* d_in, const int* in_sizes, int n_in,
                              void* d_out, int out_size, void* d_ws, size_t ws_size,
                              hipStream_t stream){
  const float* f     = (const float*)d_in[0];
  const float* alpha = (const float*)d_in[1];
  const float* wg    = (const float*)d_in[2];
  const float* bg    = (const float*)d_in[3];
  const float* wbar  = (const float*)d_in[4];
  const float* u     = (const float*)d_in[5];
  (void)in_sizes; (void)n_in; (void)out_size; (void)ws_size;
  float* out = (float*)d_out;

  char* ws = (char*)d_ws;
  float*    stats  = (float*)ws;                       // 256 B
  float*    stats2 = (float*)(ws + 4096);              // 256 B
  unsigned* wsnb   = (unsigned*)(ws + 8192);           // 2 KB
  unsigned* wgb    = (unsigned*)(ws + 16384);          // 16 KB
  unsigned* apm    = (unsigned*)(ws + 65536);                                   // 32 MB
  unsigned* gn     = (unsigned*)(ws + 65536 + (size_t)NPIXc*64);                // 64 MB
  unsigned* y2     = (unsigned*)(ws + 65536 + (size_t)NPIXc*64 + (size_t)NPIXc*128); // 32 MB

  hipMemsetAsync(stats, 0, 64 * sizeof(float), stream);
  k0_prep  <<<1, 64, 0, stream>>>(wbar, u, wg, wsnb, wgb);
  k1_gn    <<<NPIXc / 256, 256, 0, stream>>>(f, wgb, bg, gn);
  k2a_at   <<<NPIXc / 256, 256, 0, stream>>>(alpha, wsnb, apm);
  k2_agg   <<<2048, 256, 0, stream>>>(gn, apm, y2);
  k3_stats <<<256, 256, 0, stream>>>(y2, stats);
  k3b_final<<<1, 64, 0, stream>>>(stats, stats2);
  k4_out   <<<NPIXc / 256, 256, 0, stream>>>(y2, alpha, stats2, out);
}